// Round 11
// baseline (74.225 us; speedup 1.0000x reference)
//
#include <hip/hip_runtime.h>
#include <stdint.h>

#define NUM_NODES 50000
#define B_ 4096
#define N_ 100

typedef float f32x4 __attribute__((ext_vector_type(4)));
typedef int   i32x4 __attribute__((ext_vector_type(4)));
typedef short s16x8 __attribute__((ext_vector_type(8)));

__device__ inline unsigned short f2bf(float f) {
    unsigned u = __float_as_uint(f);
    u += 0x7fffu + ((u >> 16) & 1u);
    return (unsigned short)(u >> 16);
}

// wave64 sum-reduce on the VALU pipe (DPP), result broadcast to all lanes.
template <int CTRL>
__device__ inline float dpp_add(float x) {
    int t = __builtin_amdgcn_update_dpp(0, __float_as_int(x), CTRL, 0xf, 0xf, true);
    return x + __int_as_float(t);
}
__device__ inline float wave_sum64(float x) {
    x = dpp_add<0x111>(x);   // row_shr:1
    x = dpp_add<0x112>(x);   // row_shr:2
    x = dpp_add<0x114>(x);   // row_shr:4
    x = dpp_add<0x118>(x);   // row_shr:8
    x = dpp_add<0x142>(x);   // row_bcast:15
    x = dpp_add<0x143>(x);   // row_bcast:31
    return __int_as_float(__builtin_amdgcn_readlane(__float_as_int(x), 63));
}

// ---------------------------------------------------------------------------
// k_pre (MFMA): blocks 0..781 -> proj = node_raw @ W_feat + b_feat, skill
//   last block -> hb, wmg[11], Mg[11][11], PGmF (bf16 frag-ready M = P'@Gg)
// ---------------------------------------------------------------------------
__global__ __launch_bounds__(256) void k_pre(
    const float* __restrict__ node_raw, const float* __restrict__ W_feat,
    const float* __restrict__ b_feat, const float* __restrict__ W_gcn,
    const float* __restrict__ ln_g, const float* __restrict__ ln_b,
    const float* __restrict__ W_edge, const float* __restrict__ b_edge,
    const float* __restrict__ W_time, const float* __restrict__ b_time,
    const float* __restrict__ W_struct, const float* __restrict__ b_struct,
    float* __restrict__ proj, int* __restrict__ skill,
    float* __restrict__ hb, float* __restrict__ wmg, float* __restrict__ Mg,
    unsigned short* __restrict__ PGmF)
{
    __shared__ float red[4][64];
    __shared__ float PGms[12][64];              // 3 KiB
    __shared__ unsigned short WfB[16][64][8];   // 16 KiB frag-ready W_feat
    int blk = blockIdx.x;
    int t = threadIdx.x;
    int dj = t & 63;

    if (blk == gridDim.x - 1) {             // params block
        int g = t >> 6;
        float acc = 0.f;
        #pragma unroll
        for (int i = 0; i < 16; ++i) {
            int dk = g * 16 + i;
            acc += ln_b[dk] * W_gcn[dk * 64 + dj];
        }
        red[g][dj] = acc;

        if (t < 64) {
            int d = t;
            // column means + centered Gram (R7-verified)
            float col[11];
            col[0] = W_edge[d];
            col[1] = W_struct[d];
            #pragma unroll
            for (int i = 0; i < 8; ++i) col[2 + i] = W_time[i * 64 + d];
            col[10] = b_edge[d] + b_time[d] + 2.f * b_struct[d];
            float wmv[11];
            #pragma unroll
            for (int j = 0; j < 11; ++j) wmv[j] = wave_sum64(col[j]) * (1.f / 64.f);
            float cc[11];
            #pragma unroll
            for (int j = 0; j < 11; ++j) cc[j] = col[j] - wmv[j];
            #pragma unroll
            for (int j = 0; j < 11; ++j) {
                #pragma unroll
                for (int k = j; k < 11; ++k) {
                    float m = wave_sum64(cc[j] * cc[k]);
                    if (t == 0) { Mg[j * 11 + k] = m; Mg[k * 11 + j] = m; }
                }
            }
            if (t == 0) {
                #pragma unroll
                for (int j = 0; j < 11; ++j) wmg[j] = wmv[j];
            }

            // M = [P' @ Gg ; colsum(Gg)], Gg = diag(ln_g)@W_gcn (R7-verified PGm)
            int j = t;   // output col
            float accp[12];
            #pragma unroll
            for (int m = 0; m < 12; ++m) accp[m] = 0.f;
            for (int d2 = 0; d2 < 64; ++d2) {
                float gg = ln_g[d2] * W_gcn[d2 * 64 + j];
                float bias_d = b_edge[d2] + b_time[d2] + 2.f * b_struct[d2];
                accp[0] = fmaf(W_edge[d2], gg, accp[0]);
                accp[1] = fmaf(W_struct[d2], gg, accp[1]);
                #pragma unroll
                for (int i = 0; i < 8; ++i)
                    accp[2 + i] = fmaf(W_time[i * 64 + d2], gg, accp[2 + i]);
                accp[10] = fmaf(bias_d, gg, accp[10]);
                accp[11] += gg;
            }
            #pragma unroll
            for (int m = 0; m < 12; ++m) PGms[m][j] = accp[m];
        }
        __syncthreads();
        if (g == 0) hb[dj] = red[0][dj] + red[1][dj] + red[2][dj] + red[3][dj];

        // frag-pack M -> PGmF: B-frag lane l of col-tile ct holds k=(l>>4)*8..+8
        {
            int ct = t >> 6, l = t & 63;
            int col = ct * 16 + (l & 15);
            int ks = (l >> 4) * 8;
            s16x8 a2;
            #pragma unroll
            for (int j2 = 0; j2 < 8; ++j2) {
                int k = ks + j2;
                a2[j2] = (k < 12) ? (short)f2bf(PGms[k][col]) : (short)0;
            }
            *(s16x8*)(PGmF + ((size_t)ct * 64 + l) * 8) = a2;
        }
        return;
    }

    // stage W_feat frag-ready
    #pragma unroll
    for (int i = 0; i < 4; ++i) {
        int e = t + i * 256;
        int tile = e >> 6;
        int l = e & 63;
        int ct = tile >> 2, kt = tile & 3;
        int col = ct * 16 + (l & 15);
        int ks = kt * 32 + (l >> 4) * 8;
        s16x8 a;
        #pragma unroll
        for (int j = 0; j < 8; ++j)
            a[j] = (short)f2bf(W_feat[(ks + j) * 64 + col]);
        *(s16x8*)&WfB[tile][l][0] = a;
    }
    __syncthreads();

    int w = t >> 6, lane = t & 63;
    int rbase = blk * 64 + w * 16;
    int rA = rbase + (lane & 15);
    int rc = rA < NUM_NODES ? rA : (NUM_NODES - 1);
    int kq = lane >> 4;

    s16x8 A[4];
    float a0x = 0.f;
    #pragma unroll
    for (int kt = 0; kt < 4; ++kt) {
        const float* src = node_raw + (size_t)rc * 128 + kt * 32 + kq * 8;
        f32x4 v0 = *(const f32x4*)src;
        f32x4 v1 = *(const f32x4*)(src + 4);
        s16x8 a;
        a[0] = (short)f2bf(v0.x); a[1] = (short)f2bf(v0.y);
        a[2] = (short)f2bf(v0.z); a[3] = (short)f2bf(v0.w);
        a[4] = (short)f2bf(v1.x); a[5] = (short)f2bf(v1.y);
        a[6] = (short)f2bf(v1.z); a[7] = (short)f2bf(v1.w);
        A[kt] = a;
        if (kt == 0) a0x = v0.x;
    }
    if (kq == 0 && rA < NUM_NODES) skill[rA] = (int)a0x;

    f32x4 acc[4];
    #pragma unroll
    for (int ct = 0; ct < 4; ++ct) { f32x4 z = {0.f,0.f,0.f,0.f}; acc[ct] = z; }
    #pragma unroll
    for (int ct = 0; ct < 4; ++ct) {
        #pragma unroll
        for (int kt = 0; kt < 4; ++kt) {
            s16x8 bfr = *(const s16x8*)&WfB[ct * 4 + kt][lane][0];
            acc[ct] = __builtin_amdgcn_mfma_f32_16x16x32_bf16(A[kt], bfr, acc[ct], 0, 0, 0);
        }
    }
    #pragma unroll
    for (int ct = 0; ct < 4; ++ct) {
        int col = ct * 16 + (lane & 15);
        float bf = b_feat[col];
        #pragma unroll
        for (int j = 0; j < 4; ++j) {
            int row = rbase + kq * 4 + j;
            if (row < NUM_NODES)
                proj[(size_t)row * 64 + col] = acc[ct][j] + bf;
        }
    }
}

// ---------------------------------------------------------------------------
// k_pg (MFMA): projG = proj @ (diag(ln_g)@W_gcn). Split-bf16 A for accuracy.
// ---------------------------------------------------------------------------
__global__ __launch_bounds__(256) void k_pg(
    const float* __restrict__ proj, const float* __restrict__ W_gcn,
    const float* __restrict__ ln_g, float* __restrict__ projG)
{
    __shared__ unsigned short WgB[8][64][8];   // 8 KiB frag-ready Gg
    int t = threadIdx.x;
    #pragma unroll
    for (int i = 0; i < 2; ++i) {
        int e = t + i * 256;
        int tile = e >> 6, l = e & 63;
        int ct = tile >> 1, kt = tile & 1;
        int col = ct * 16 + (l & 15);
        int ks = kt * 32 + (l >> 4) * 8;
        s16x8 a;
        #pragma unroll
        for (int j = 0; j < 8; ++j)
            a[j] = (short)f2bf(ln_g[ks + j] * W_gcn[(ks + j) * 64 + col]);
        *(s16x8*)&WgB[tile][l][0] = a;
    }
    __syncthreads();

    int w = t >> 6, lane = t & 63;
    int rbase = blockIdx.x * 64 + w * 16;
    int rA = rbase + (lane & 15);
    int rc = rA < NUM_NODES ? rA : (NUM_NODES - 1);
    int kq = lane >> 4;

    s16x8 Ahi[2], Alo[2];
    #pragma unroll
    for (int kt = 0; kt < 2; ++kt) {
        const float* src = proj + (size_t)rc * 64 + kt * 32 + kq * 8;
        f32x4 v0 = *(const f32x4*)src;
        f32x4 v1 = *(const f32x4*)(src + 4);
        #pragma unroll
        for (int j = 0; j < 8; ++j) {
            float v = (j < 4) ? v0[j] : v1[j - 4];
            unsigned short hi = f2bf(v);
            float rem = v - __uint_as_float((unsigned)hi << 16);
            Ahi[kt][j] = (short)hi;
            Alo[kt][j] = (short)f2bf(rem);
        }
    }
    f32x4 acc[4];
    #pragma unroll
    for (int ct = 0; ct < 4; ++ct) { f32x4 z = {0.f,0.f,0.f,0.f}; acc[ct] = z; }
    #pragma unroll
    for (int ct = 0; ct < 4; ++ct) {
        #pragma unroll
        for (int kt = 0; kt < 2; ++kt) {
            s16x8 bfr = *(const s16x8*)&WgB[ct * 2 + kt][lane][0];
            acc[ct] = __builtin_amdgcn_mfma_f32_16x16x32_bf16(Alo[kt], bfr, acc[ct], 0, 0, 0);
            acc[ct] = __builtin_amdgcn_mfma_f32_16x16x32_bf16(Ahi[kt], bfr, acc[ct], 0, 0, 0);
        }
    }
    #pragma unroll
    for (int ct = 0; ct < 4; ++ct) {
        int col = ct * 16 + (lane & 15);
        #pragma unroll
        for (int j = 0; j < 4; ++j) {
            int row = rbase + kq * 4 + j;
            if (row < NUM_NODES)
                projG[(size_t)row * 64 + col] = acc[ct][j];
        }
    }
}

// ---------------------------------------------------------------------------
// k_stat: per-node LN stats (R7-verified). stats[node][16] = {pm, pc2, pcw[0..10]}
// ---------------------------------------------------------------------------
__global__ __launch_bounds__(256) void k_stat(
    const float* __restrict__ proj,
    const float* __restrict__ W_edge, const float* __restrict__ b_edge,
    const float* __restrict__ W_time, const float* __restrict__ b_time,
    const float* __restrict__ W_struct, const float* __restrict__ b_struct,
    const float* __restrict__ wmg, float* __restrict__ stats)
{
    __shared__ float T[256][65];
    __shared__ float Wc[64][12];
    int t = threadIdx.x;
    int base = blockIdx.x * 256;

    if (t < 64) {
        int d = t;
        Wc[d][0] = W_edge[d];
        Wc[d][1] = W_struct[d];
        #pragma unroll
        for (int i = 0; i < 8; ++i) Wc[d][2 + i] = W_time[i * 64 + d];
        Wc[d][10] = b_edge[d] + b_time[d] + 2.f * b_struct[d];
        Wc[d][11] = 0.f;
    }

    int w = t >> 6, lane = t & 63;
    #pragma unroll 4
    for (int it = 0; it < 64; ++it) {
        int row = it * 4 + w;
        int node = base + row;
        int rc = node < NUM_NODES ? node : (NUM_NODES - 1);
        T[row][lane] = proj[(size_t)rc * 64 + lane];
    }
    __syncthreads();

    float sp = 0.f, spp = 0.f;
    float pw[11];
    #pragma unroll
    for (int j = 0; j < 11; ++j) pw[j] = 0.f;

    for (int d = 0; d < 64; ++d) {
        float p = T[t][d];
        f32x4 c0 = *(const f32x4*)&Wc[d][0];
        f32x4 c1 = *(const f32x4*)&Wc[d][4];
        f32x4 c2 = *(const f32x4*)&Wc[d][8];
        sp += p;
        spp = fmaf(p, p, spp);
        pw[0] = fmaf(p, c0.x, pw[0]);
        pw[1] = fmaf(p, c0.y, pw[1]);
        pw[2] = fmaf(p, c0.z, pw[2]);
        pw[3] = fmaf(p, c0.w, pw[3]);
        pw[4] = fmaf(p, c1.x, pw[4]);
        pw[5] = fmaf(p, c1.y, pw[5]);
        pw[6] = fmaf(p, c1.z, pw[6]);
        pw[7] = fmaf(p, c1.w, pw[7]);
        pw[8] = fmaf(p, c2.x, pw[8]);
        pw[9] = fmaf(p, c2.y, pw[9]);
        pw[10] = fmaf(p, c2.z, pw[10]);
    }

    int node = base + t;
    if (node < NUM_NODES) {
        float o[16];
        o[0] = sp * (1.f / 64.f);
        o[1] = spp - sp * sp * (1.f / 64.f);
        #pragma unroll
        for (int j = 0; j < 11; ++j) o[2 + j] = pw[j] - sp * wmg[j];
        o[13] = 0.f; o[14] = 0.f; o[15] = 0.f;
        float* dst = stats + (size_t)node * 16;
        #pragma unroll
        for (int q = 0; q < 4; ++q) *(f32x4*)(dst + q * 4) = *(f32x4*)&o[q * 4];
    }
}

// ---------------------------------------------------------------------------
// k_main: one block per sample. NO Phase A: staging computes V (bf16, frag-
//   ready LDS) + rstd; h = rstd*projG_gather + MFMA(V, M) + hb; chain+pool+out.
// ---------------------------------------------------------------------------
__global__ __launch_bounds__(256) void k_main(
    const int* __restrict__ ids, const int* __restrict__ eids,
    const float* __restrict__ times, const int* __restrict__ dst_ids,
    const float* __restrict__ edge_raw,
    const float* __restrict__ w_tenc, const float* __restrict__ b_tenc,
    const float* __restrict__ b_gcn, const float* __restrict__ W_out,
    const float* __restrict__ b_out,
    const float* __restrict__ proj, const float* __restrict__ projG,
    const int* __restrict__ skill,
    const float* __restrict__ hb, const float* __restrict__ wmg,
    const float* __restrict__ Mg, const unsigned short* __restrict__ PGmF,
    const float* __restrict__ stats,
    float* __restrict__ out)
{
    __shared__ int ids_s[112];
    __shared__ unsigned short VA[112 * 32];   // 7 KiB bf16 V, chunk-swizzled
    __shared__ float rstd_s[112];
    __shared__ float pooled[64];
    __shared__ float x2[64];
    __shared__ int vcnt_w[4];

    int b = blockIdx.x;
    int t = threadIdx.x;
    int lane = t & 63, w = t >> 6;

    int dstb = dst_ids[b];
    int skdst = skill[dstb];

    // -------- staging: per-neighbor V + rstd --------
    int idx_c = t < N_ ? t : 0;
    int id_t = ids[b * N_ + idx_c];
    float tm_t = times[b * N_ + idx_c];
    int ei_t = eids[b * N_ + idx_c];
    float e_t = edge_raw[(size_t)ei_t * 128];
    int sk_t = skill[id_t];
    unsigned long long bal = __ballot((t < N_) && (id_t > 0));
    if (lane == 0) vcnt_w[w] = __popcll(bal);

    if (t < N_) {
        ids_s[t] = id_t;
        float u[11];
        u[0] = e_t;
        u[1] = (id_t == dstb ? 1.f : 0.f) + (sk_t == skdst ? 1.f : 0.f);
        #pragma unroll
        for (int i = 0; i < 8; ++i) u[2 + i] = __cosf(fmaf(tm_t, w_tenc[i], b_tenc[i]));
        u[10] = 1.f;

        const f32x4* sp = (const f32x4*)(stats + (size_t)id_t * 16);
        f32x4 s0 = sp[0], s1 = sp[1], s2 = sp[2], s3 = sp[3];
        float pwv[11] = {s0.z, s0.w, s1.x, s1.y, s1.z, s1.w,
                         s2.x, s2.y, s2.z, s2.w, s3.x};
        float mu = s0.x, q = s0.y;
        #pragma unroll
        for (int j = 0; j < 11; ++j) {
            mu = fmaf(u[j], wmg[j], mu);
            q = fmaf(2.f * u[j], pwv[j], q);
        }
        #pragma unroll
        for (int j = 0; j < 11; ++j) {
            float tj = 0.f;
            #pragma unroll
            for (int k = 0; k < 11; ++k) tj = fmaf(Mg[j * 11 + k], u[k], tj);
            q = fmaf(u[j], tj, q);
        }
        float rstd = rsqrtf(fmaxf(q, 0.f) * (1.f / 64.f) + 1e-5f);
        rstd_s[t] = rstd;

        unsigned short vv[32];
        #pragma unroll
        for (int j = 0; j < 11; ++j) vv[j] = f2bf(rstd * u[j]);
        vv[11] = f2bf(-rstd * mu);
        #pragma unroll
        for (int j = 12; j < 32; ++j) vv[j] = 0;
        #pragma unroll
        for (int c = 0; c < 4; ++c)
            *(s16x8*)((char*)VA + t * 64 + ((c ^ (t & 3)) * 16)) = *(const s16x8*)&vv[c * 8];
    } else if (t < 112) {                    // pad rows
        ids_s[t] = 0;
        rstd_s[t] = 0.f;
        s16x8 z = {0, 0, 0, 0, 0, 0, 0, 0};
        #pragma unroll
        for (int c = 0; c < 4; ++c)
            *(s16x8*)((char*)VA + t * 64 + c * 16) = z;
    }
    if (w == 2) x2[lane] = proj[(size_t)dstb * 64 + lane];
    __syncthreads();
    int v = vcnt_w[0] + vcnt_w[1] + vcnt_w[2] + vcnt_w[3];

    // -------- Phase B: gathers first (latency), then MFMA --------
    int colw = 16 * w + (lane & 15);
    int kq = lane >> 4;

    float pgv[7][4];
    #pragma unroll
    for (int mt = 0; mt < 7; ++mt) {
        i32x4 s4 = *(const i32x4*)&ids_s[mt * 16 + kq * 4];
        #pragma unroll
        for (int j = 0; j < 4; ++j)
            pgv[mt][j] = projG[(size_t)s4[j] * 64 + colw];
    }

    s16x8 bfr = *(const s16x8*)(PGmF + ((size_t)w * 64 + lane) * 8);

    f32x4 acc[7];
    #pragma unroll
    for (int mt = 0; mt < 7; ++mt) {
        int row = mt * 16 + (lane & 15);
        s16x8 a = *(const s16x8*)((char*)VA + row * 64 + ((kq ^ (row & 3)) * 16));
        f32x4 z = {0.f, 0.f, 0.f, 0.f};
        acc[mt] = __builtin_amdgcn_mfma_f32_16x16x32_bf16(a, bfr, z, 0, 0, 0);
    }

    // -------- Phase C: combine + chain + relu + pool --------
    float hbv = hb[colw], bgc = b_gcn[colw];
    float carry = 0.f, po = 0.f;
    #pragma unroll
    for (int mt = 0; mt < 7; ++mt) {
        f32x4 rs4 = *(const f32x4*)&rstd_s[mt * 16 + kq * 4];
        float hh[4];
        #pragma unroll
        for (int j = 0; j < 4; ++j)
            hh[j] = fmaf(rs4[j], pgv[mt][j], acc[mt][j]) + hbv;

        float hup = __shfl_up(hh[3], 16, 64);
        float hpj = (kq > 0) ? hup : carry;
        int nb = mt * 16 + kq * 4;
        #pragma unroll
        for (int j = 0; j < 4; ++j) {
            int nn = nb + j;
            bool hin = (nn >= 1) && (nn < v);
            float a_ = hin ? 0.5f : 1.f;
            float dprev = (nn >= 2 && nn <= v) ? 0.70710678118f : 1.f;
            float coef = hin ? dprev * 0.70710678118f : 0.f;
            float o = hh[j] * a_ + coef * hpj + bgc;
            po += (nn < N_) ? fmaxf(o, 0.f) : 0.f;
            hpj = hh[j];
        }
        carry = __shfl(hh[3], 48 + (lane & 15), 64);
    }
    po += __shfl_xor(po, 16, 64);
    po += __shfl_xor(po, 32, 64);
    if (lane < 16) pooled[colw] = po * (1.f / (float)N_);
    __syncthreads();

    // -------- Phase D: output projections --------
    if (w == 0) {
        float o = b_out[lane];
        #pragma unroll
        for (int dk4 = 0; dk4 < 16; ++dk4) {
            f32x4 p4 = *(const f32x4*)&pooled[dk4 * 4];
            o = fmaf(p4.x, W_out[(dk4 * 4 + 0) * 64 + lane], o);
            o = fmaf(p4.y, W_out[(dk4 * 4 + 1) * 64 + lane], o);
            o = fmaf(p4.z, W_out[(dk4 * 4 + 2) * 64 + lane], o);
            o = fmaf(p4.w, W_out[(dk4 * 4 + 3) * 64 + lane], o);
        }
        out[(size_t)b * 64 + lane] = o;
    } else if (w == 1) {
        float o = b_out[lane];
        #pragma unroll
        for (int dk4 = 0; dk4 < 16; ++dk4) {
            f32x4 p4 = *(const f32x4*)&x2[dk4 * 4];
            o = fmaf(p4.x, W_out[(dk4 * 4 + 0) * 64 + lane], o);
            o = fmaf(p4.y, W_out[(dk4 * 4 + 1) * 64 + lane], o);
            o = fmaf(p4.z, W_out[(dk4 * 4 + 2) * 64 + lane], o);
            o = fmaf(p4.w, W_out[(dk4 * 4 + 3) * 64 + lane], o);
        }
        out[(size_t)(B_ + b) * 64 + lane] = o;
    }
}

// ---------------------------------------------------------------------------
extern "C" void kernel_launch(void* const* d_in, const int* in_sizes, int n_in,
                              void* d_out, int out_size, void* d_ws, size_t ws_size,
                              hipStream_t stream)
{
    const int*   ids      = (const int*)d_in[0];
    const int*   eids     = (const int*)d_in[1];
    const float* times    = (const float*)d_in[2];
    const int*   dst_ids  = (const int*)d_in[3];
    const float* node_raw = (const float*)d_in[4];
    const float* edge_raw = (const float*)d_in[5];
    const float* W_feat   = (const float*)d_in[6];
    const float* b_feat   = (const float*)d_in[7];
    const float* W_edge   = (const float*)d_in[8];
    const float* b_edge   = (const float*)d_in[9];
    const float* W_time   = (const float*)d_in[10];
    const float* b_time   = (const float*)d_in[11];
    const float* W_struct = (const float*)d_in[12];
    const float* b_struct = (const float*)d_in[13];
    const float* w_tenc   = (const float*)d_in[14];
    const float* b_tenc   = (const float*)d_in[15];
    const float* ln_g     = (const float*)d_in[16];
    const float* ln_b     = (const float*)d_in[17];
    const float* W_gcn    = (const float*)d_in[18];
    const float* b_gcn    = (const float*)d_in[19];
    const float* W_out    = (const float*)d_in[20];
    const float* b_out    = (const float*)d_in[21];

    char* ws = (char*)d_ws;
    float*          proj   = (float*)ws;                          // 12,800,000 B
    int*            skill  = (int*)(ws + 12800000);               //    200,000 B
    float*          hb     = (float*)(ws + 13008192);             //        256 B
    float*          wmg    = (float*)(ws + 13008448);             //         64 B
    float*          Mg     = (float*)(ws + 13008512);             //        512 B
    unsigned short* PGmF   = (unsigned short*)(ws + 13009024);    //      4,096 B
    float*          stats  = (float*)(ws + 13100032);             //  3,200,000 B
    float*          projG  = (float*)(ws + 16400000);             // 12,800,000 B

    k_pre<<<783, 256, 0, stream>>>(node_raw, W_feat, b_feat, W_gcn, ln_g, ln_b,
                                   W_edge, b_edge, W_time, b_time, W_struct, b_struct,
                                   proj, skill, hb, wmg, Mg, PGmF);
    k_stat<<<196, 256, 0, stream>>>(proj, W_edge, b_edge, W_time, b_time,
                                    W_struct, b_struct, wmg, stats);
    k_pg<<<782, 256, 0, stream>>>(proj, W_gcn, ln_g, projG);
    k_main<<<B_, 256, 0, stream>>>(ids, eids, times, dst_ids, edge_raw,
                                   w_tenc, b_tenc, b_gcn, W_out, b_out,
                                   proj, projG, skill, hb, wmg, Mg, PGmF, stats,
                                   (float*)d_out);
}

// Round 12
// 70.408 us; speedup vs baseline: 1.0542x; 1.0542x over previous
//
#include <hip/hip_runtime.h>
#include <stdint.h>

#define NUM_NODES 50000
#define B_ 4096
#define N_ 100

typedef float f32x4 __attribute__((ext_vector_type(4)));
typedef float f32x2 __attribute__((ext_vector_type(2)));
typedef int   i32x4 __attribute__((ext_vector_type(4)));
typedef short s16x8 __attribute__((ext_vector_type(8)));

__device__ inline unsigned short f2bf(float f) {
    unsigned u = __float_as_uint(f);
    u += 0x7fffu + ((u >> 16) & 1u);
    return (unsigned short)(u >> 16);
}

// wave64 sum-reduce on the VALU pipe (DPP), result broadcast to all lanes.
template <int CTRL>
__device__ inline float dpp_add(float x) {
    int t = __builtin_amdgcn_update_dpp(0, __float_as_int(x), CTRL, 0xf, 0xf, true);
    return x + __int_as_float(t);
}
__device__ inline float wave_sum64(float x) {
    x = dpp_add<0x111>(x);
    x = dpp_add<0x112>(x);
    x = dpp_add<0x114>(x);
    x = dpp_add<0x118>(x);
    x = dpp_add<0x142>(x);
    x = dpp_add<0x143>(x);
    return __int_as_float(__builtin_amdgcn_readlane(__float_as_int(x), 63));
}

// ---------------------------------------------------------------------------
// k_pre (MFMA): blocks 0..781 -> proj = node_raw @ W_feat + b_feat, skill
//   last block -> hb, wmg[11], Mg[11][11], PGmF (bf16 frag-ready M)
// ---------------------------------------------------------------------------
__global__ __launch_bounds__(256) void k_pre(
    const float* __restrict__ node_raw, const float* __restrict__ W_feat,
    const float* __restrict__ b_feat, const float* __restrict__ W_gcn,
    const float* __restrict__ ln_g, const float* __restrict__ ln_b,
    const float* __restrict__ W_edge, const float* __restrict__ b_edge,
    const float* __restrict__ W_time, const float* __restrict__ b_time,
    const float* __restrict__ W_struct, const float* __restrict__ b_struct,
    float* __restrict__ proj, int* __restrict__ skill,
    float* __restrict__ hb, float* __restrict__ wmg, float* __restrict__ Mg,
    unsigned short* __restrict__ PGmF)
{
    __shared__ float red[4][64];
    __shared__ float PGms[12][64];
    __shared__ unsigned short WfB[16][64][8];
    int blk = blockIdx.x;
    int t = threadIdx.x;
    int dj = t & 63;

    if (blk == gridDim.x - 1) {             // params block
        int g = t >> 6;
        float acc = 0.f;
        #pragma unroll
        for (int i = 0; i < 16; ++i) {
            int dk = g * 16 + i;
            acc += ln_b[dk] * W_gcn[dk * 64 + dj];
        }
        red[g][dj] = acc;

        if (t < 64) {
            int d = t;
            float col[11];
            col[0] = W_edge[d];
            col[1] = W_struct[d];
            #pragma unroll
            for (int i = 0; i < 8; ++i) col[2 + i] = W_time[i * 64 + d];
            col[10] = b_edge[d] + b_time[d] + 2.f * b_struct[d];
            float wmv[11];
            #pragma unroll
            for (int j = 0; j < 11; ++j) wmv[j] = wave_sum64(col[j]) * (1.f / 64.f);
            float cc[11];
            #pragma unroll
            for (int j = 0; j < 11; ++j) cc[j] = col[j] - wmv[j];
            #pragma unroll
            for (int j = 0; j < 11; ++j) {
                #pragma unroll
                for (int k = j; k < 11; ++k) {
                    float m = wave_sum64(cc[j] * cc[k]);
                    if (t == 0) { Mg[j * 11 + k] = m; Mg[k * 11 + j] = m; }
                }
            }
            if (t == 0) {
                #pragma unroll
                for (int j = 0; j < 11; ++j) wmg[j] = wmv[j];
            }

            int j = t;
            float accp[12];
            #pragma unroll
            for (int m = 0; m < 12; ++m) accp[m] = 0.f;
            for (int d2 = 0; d2 < 64; ++d2) {
                float gg = ln_g[d2] * W_gcn[d2 * 64 + j];
                float bias_d = b_edge[d2] + b_time[d2] + 2.f * b_struct[d2];
                accp[0] = fmaf(W_edge[d2], gg, accp[0]);
                accp[1] = fmaf(W_struct[d2], gg, accp[1]);
                #pragma unroll
                for (int i = 0; i < 8; ++i)
                    accp[2 + i] = fmaf(W_time[i * 64 + d2], gg, accp[2 + i]);
                accp[10] = fmaf(bias_d, gg, accp[10]);
                accp[11] += gg;
            }
            #pragma unroll
            for (int m = 0; m < 12; ++m) PGms[m][j] = accp[m];
        }
        __syncthreads();
        if (g == 0) hb[dj] = red[0][dj] + red[1][dj] + red[2][dj] + red[3][dj];

        {
            int ct = t >> 6, l = t & 63;
            int col = ct * 16 + (l & 15);
            int ks = (l >> 4) * 8;
            s16x8 a2;
            #pragma unroll
            for (int j2 = 0; j2 < 8; ++j2) {
                int k = ks + j2;
                a2[j2] = (k < 12) ? (short)f2bf(PGms[k][col]) : (short)0;
            }
            *(s16x8*)(PGmF + ((size_t)ct * 64 + l) * 8) = a2;
        }
        return;
    }

    #pragma unroll
    for (int i = 0; i < 4; ++i) {
        int e = t + i * 256;
        int tile = e >> 6;
        int l = e & 63;
        int ct = tile >> 2, kt = tile & 3;
        int col = ct * 16 + (l & 15);
        int ks = kt * 32 + (l >> 4) * 8;
        s16x8 a;
        #pragma unroll
        for (int j = 0; j < 8; ++j)
            a[j] = (short)f2bf(W_feat[(ks + j) * 64 + col]);
        *(s16x8*)&WfB[tile][l][0] = a;
    }
    __syncthreads();

    int w = t >> 6, lane = t & 63;
    int rbase = blk * 64 + w * 16;
    int rA = rbase + (lane & 15);
    int rc = rA < NUM_NODES ? rA : (NUM_NODES - 1);
    int kq = lane >> 4;

    s16x8 A[4];
    float a0x = 0.f;
    #pragma unroll
    for (int kt = 0; kt < 4; ++kt) {
        const float* src = node_raw + (size_t)rc * 128 + kt * 32 + kq * 8;
        f32x4 v0 = *(const f32x4*)src;
        f32x4 v1 = *(const f32x4*)(src + 4);
        s16x8 a;
        a[0] = (short)f2bf(v0.x); a[1] = (short)f2bf(v0.y);
        a[2] = (short)f2bf(v0.z); a[3] = (short)f2bf(v0.w);
        a[4] = (short)f2bf(v1.x); a[5] = (short)f2bf(v1.y);
        a[6] = (short)f2bf(v1.z); a[7] = (short)f2bf(v1.w);
        A[kt] = a;
        if (kt == 0) a0x = v0.x;
    }
    if (kq == 0 && rA < NUM_NODES) skill[rA] = (int)a0x;

    f32x4 acc[4];
    #pragma unroll
    for (int ct = 0; ct < 4; ++ct) { f32x4 z = {0.f,0.f,0.f,0.f}; acc[ct] = z; }
    #pragma unroll
    for (int ct = 0; ct < 4; ++ct) {
        #pragma unroll
        for (int kt = 0; kt < 4; ++kt) {
            s16x8 bfr = *(const s16x8*)&WfB[ct * 4 + kt][lane][0];
            acc[ct] = __builtin_amdgcn_mfma_f32_16x16x32_bf16(A[kt], bfr, acc[ct], 0, 0, 0);
        }
    }
    #pragma unroll
    for (int ct = 0; ct < 4; ++ct) {
        int col = ct * 16 + (lane & 15);
        float bf = b_feat[col];
        #pragma unroll
        for (int j = 0; j < 4; ++j) {
            int row = rbase + kq * 4 + j;
            if (row < NUM_NODES)
                proj[(size_t)row * 64 + col] = acc[ct][j] + bf;
        }
    }
}

// ---------------------------------------------------------------------------
// k_pg (MFMA, fused): from proj rows (split-bf16 A-frags) compute
//   projG = proj @ (diag(ln_g)@W_gcn)          (f32-level via hi/lo split)
//   dstE  = proj @ W_out + b_out
//   stats[node][16]: cols 0..10 = proj·statcol_j (raw), 11 = rowsum, 12 = rowsum(p^2)
// ---------------------------------------------------------------------------
__global__ __launch_bounds__(256) void k_pg(
    const float* __restrict__ proj, const float* __restrict__ W_gcn,
    const float* __restrict__ ln_g,
    const float* __restrict__ W_out, const float* __restrict__ b_out,
    const float* __restrict__ W_edge, const float* __restrict__ b_edge,
    const float* __restrict__ W_time, const float* __restrict__ b_time,
    const float* __restrict__ W_struct, const float* __restrict__ b_struct,
    float* __restrict__ projG, float* __restrict__ dstE,
    float* __restrict__ stats)
{
    __shared__ unsigned short WgB[8][64][8];
    __shared__ unsigned short WoB[8][64][8];
    __shared__ unsigned short WsB[2][64][8];
    int t = threadIdx.x;

    #pragma unroll
    for (int i = 0; i < 2; ++i) {
        int e = t + i * 256;
        int tile = e >> 6, l = e & 63;
        int ct = tile >> 1, kt = tile & 1;
        int col = ct * 16 + (l & 15);
        int ks = kt * 32 + (l >> 4) * 8;
        s16x8 a, b2;
        #pragma unroll
        for (int j = 0; j < 8; ++j) {
            int k = ks + j;
            a[j]  = (short)f2bf(ln_g[k] * W_gcn[k * 64 + col]);
            b2[j] = (short)f2bf(W_out[k * 64 + col]);
        }
        *(s16x8*)&WgB[tile][l][0] = a;
        *(s16x8*)&WoB[tile][l][0] = b2;
    }
    if (t < 128) {
        int kt = t >> 6, l = t & 63;
        int col = l & 15;
        int ks = kt * 32 + (l >> 4) * 8;
        s16x8 a;
        #pragma unroll
        for (int j = 0; j < 8; ++j) {
            int d = ks + j;
            float v;
            if (col == 0) v = W_edge[d];
            else if (col == 1) v = W_struct[d];
            else if (col < 10) v = W_time[(col - 2) * 64 + d];
            else if (col == 10) v = b_edge[d] + b_time[d] + 2.f * b_struct[d];
            else if (col == 11) v = 1.f;
            else v = 0.f;
            a[j] = (short)f2bf(v);
        }
        *(s16x8*)&WsB[kt][l][0] = a;
    }
    __syncthreads();

    int w = t >> 6, lane = t & 63;
    int rbase = blockIdx.x * 64 + w * 16;
    int rA = rbase + (lane & 15);
    int rc = rA < NUM_NODES ? rA : (NUM_NODES - 1);
    int kq = lane >> 4;

    s16x8 Ahi[2], Alo[2], Qhi[2], Qlo[2];
    #pragma unroll
    for (int kt = 0; kt < 2; ++kt) {
        const float* src = proj + (size_t)rc * 64 + kt * 32 + kq * 8;
        f32x4 v0 = *(const f32x4*)src;
        f32x4 v1 = *(const f32x4*)(src + 4);
        #pragma unroll
        for (int j = 0; j < 8; ++j) {
            float v = (j < 4) ? v0[j] : v1[j - 4];
            unsigned short hi = f2bf(v);
            float rem = v - __uint_as_float((unsigned)hi << 16);
            Ahi[kt][j] = (short)hi;
            Alo[kt][j] = (short)f2bf(rem);
            float p2 = v * v;
            unsigned short h2 = f2bf(p2);
            float r2 = p2 - __uint_as_float((unsigned)h2 << 16);
            Qhi[kt][j] = (short)h2;
            Qlo[kt][j] = (short)f2bf(r2);
        }
    }

    f32x4 accG[4], accE[4];
    f32x4 accS = {0.f, 0.f, 0.f, 0.f}, accQ = {0.f, 0.f, 0.f, 0.f};
    #pragma unroll
    for (int ct = 0; ct < 4; ++ct) {
        f32x4 z = {0.f, 0.f, 0.f, 0.f};
        accG[ct] = z; accE[ct] = z;
    }
    #pragma unroll
    for (int ct = 0; ct < 4; ++ct) {
        #pragma unroll
        for (int kt = 0; kt < 2; ++kt) {
            s16x8 bg = *(const s16x8*)&WgB[ct * 2 + kt][lane][0];
            accG[ct] = __builtin_amdgcn_mfma_f32_16x16x32_bf16(Alo[kt], bg, accG[ct], 0, 0, 0);
            accG[ct] = __builtin_amdgcn_mfma_f32_16x16x32_bf16(Ahi[kt], bg, accG[ct], 0, 0, 0);
            s16x8 bo = *(const s16x8*)&WoB[ct * 2 + kt][lane][0];
            accE[ct] = __builtin_amdgcn_mfma_f32_16x16x32_bf16(Alo[kt], bo, accE[ct], 0, 0, 0);
            accE[ct] = __builtin_amdgcn_mfma_f32_16x16x32_bf16(Ahi[kt], bo, accE[ct], 0, 0, 0);
        }
    }
    #pragma unroll
    for (int kt = 0; kt < 2; ++kt) {
        s16x8 bs = *(const s16x8*)&WsB[kt][lane][0];
        accS = __builtin_amdgcn_mfma_f32_16x16x32_bf16(Alo[kt], bs, accS, 0, 0, 0);
        accS = __builtin_amdgcn_mfma_f32_16x16x32_bf16(Ahi[kt], bs, accS, 0, 0, 0);
        accQ = __builtin_amdgcn_mfma_f32_16x16x32_bf16(Qlo[kt], bs, accQ, 0, 0, 0);
        accQ = __builtin_amdgcn_mfma_f32_16x16x32_bf16(Qhi[kt], bs, accQ, 0, 0, 0);
    }

    #pragma unroll
    for (int ct = 0; ct < 4; ++ct) {
        int col = ct * 16 + (lane & 15);
        float bo_ = b_out[col];
        #pragma unroll
        for (int j = 0; j < 4; ++j) {
            int row = rbase + kq * 4 + j;
            if (row < NUM_NODES) {
                projG[(size_t)row * 64 + col] = accG[ct][j];
                dstE[(size_t)row * 64 + col] = accE[ct][j] + bo_;
            }
        }
    }
    int c = lane & 15;
    if (c <= 11) {
        #pragma unroll
        for (int j = 0; j < 4; ++j) {
            int row = rbase + kq * 4 + j;
            if (row < NUM_NODES) stats[(size_t)row * 16 + c] = accS[j];
        }
    }
    if (c == 11) {
        #pragma unroll
        for (int j = 0; j < 4; ++j) {
            int row = rbase + kq * 4 + j;
            if (row < NUM_NODES) stats[(size_t)row * 16 + 12] = accQ[j];
        }
    }
}

// ---------------------------------------------------------------------------
// k_main: one block per sample. Early ids + pgv-gather/compute overlap;
//   V@M via MFMA; chain coefs precomputed; dst path = row copy from dstE.
// ---------------------------------------------------------------------------
__global__ __launch_bounds__(256) void k_main(
    const int* __restrict__ ids, const int* __restrict__ eids,
    const float* __restrict__ times, const int* __restrict__ dst_ids,
    const float* __restrict__ edge_raw,
    const float* __restrict__ w_tenc, const float* __restrict__ b_tenc,
    const float* __restrict__ b_gcn, const float* __restrict__ W_out,
    const float* __restrict__ b_out,
    const float* __restrict__ projG, const float* __restrict__ dstE,
    const int* __restrict__ skill,
    const float* __restrict__ hb, const float* __restrict__ wmg,
    const float* __restrict__ Mg, const unsigned short* __restrict__ PGmF,
    const float* __restrict__ stats,
    float* __restrict__ out)
{
    __shared__ int ids_s[112];
    __shared__ unsigned short VA[112 * 32];
    __shared__ float rstd_s[112];
    __shared__ f32x2 cf_s[112];
    __shared__ float pooled[64];
    __shared__ int vcnt_w[4];

    int b = blockIdx.x;
    int t = threadIdx.x;
    int lane = t & 63, w = t >> 6;

    int dstb = dst_ids[b];
    int skdst = skill[dstb];

    // ---- pre-barrier1: coalesced loads + ballot + cos ----
    int idx_c = t < N_ ? t : 0;
    int id_t = ids[b * N_ + idx_c];
    float tm_t = times[b * N_ + idx_c];
    int ei_t = eids[b * N_ + idx_c];
    if (t < 112) ids_s[t] = (t < N_) ? id_t : 0;
    unsigned long long bal = __ballot((t < N_) && (id_t > 0));
    if (lane == 0) vcnt_w[w] = __popcll(bal);
    float tc[8];
    #pragma unroll
    for (int i = 0; i < 8; ++i) tc[i] = __cosf(fmaf(tm_t, w_tenc[i], b_tenc[i]));
    __syncthreads();   // barrier1: ids_s + vcnt ready
    int v = vcnt_w[0] + vcnt_w[1] + vcnt_w[2] + vcnt_w[3];

    // ---- issue long-latency gathers (overlap with staging compute) ----
    int colw = 16 * w + (lane & 15);
    int kq = lane >> 4;
    float pgv[7][4];
    #pragma unroll
    for (int mt = 0; mt < 7; ++mt) {
        i32x4 s4 = *(const i32x4*)&ids_s[mt * 16 + kq * 4];
        #pragma unroll
        for (int j = 0; j < 4; ++j)
            pgv[mt][j] = projG[(size_t)s4[j] * 64 + colw];
    }
    if (w == 3)   // dst embedding: plain row copy (b_out pre-added in k_pg)
        out[(size_t)(B_ + b) * 64 + lane] = dstE[(size_t)dstb * 64 + lane];

    // chain coefficients (uniform over cols)
    if (t < 112) {
        int n = t;
        bool hin = (n >= 1) && (n < v);
        float a_ = hin ? 0.5f : 1.f;
        float dprev = (n >= 2 && n <= v) ? 0.70710678118f : 1.f;
        float coef = hin ? dprev * 0.70710678118f : 0.f;
        f32x2 cf = {a_, coef};
        cf_s[t] = cf;
    }

    // ---- staging: per-neighbor V + rstd ----
    if (t < N_) {
        float e_t = edge_raw[(size_t)ei_t * 128];
        int sk_t = skill[id_t];
        const f32x4* sp4 = (const f32x4*)(stats + (size_t)id_t * 16);
        f32x4 s0 = sp4[0], s1 = sp4[1], s2 = sp4[2];
        float spp = stats[(size_t)id_t * 16 + 12];

        float u[11];
        u[0] = e_t;
        u[1] = (id_t == dstb ? 1.f : 0.f) + (sk_t == skdst ? 1.f : 0.f);
        #pragma unroll
        for (int i = 0; i < 8; ++i) u[2 + i] = tc[i];
        u[10] = 1.f;

        float pwv[11] = {s0.x, s0.y, s0.z, s0.w, s1.x, s1.y, s1.z, s1.w,
                         s2.x, s2.y, s2.z};
        float sp = s2.w;
        float dot_upw = 0.f, su_wm = 0.f;
        #pragma unroll
        for (int j = 0; j < 11; ++j) {
            dot_upw = fmaf(u[j], pwv[j], dot_upw);
            su_wm = fmaf(u[j], wmg[j], su_wm);
        }
        float mu = sp * (1.f / 64.f) + su_wm;
        float q = spp + sp * sp * (1.f / 64.f) + 2.f * dot_upw - 2.f * sp * mu;
        #pragma unroll
        for (int j = 0; j < 11; ++j) {
            float tj = 0.f;
            #pragma unroll
            for (int k = 0; k < 11; ++k) tj = fmaf(Mg[j * 11 + k], u[k], tj);
            q = fmaf(u[j], tj, q);
        }
        float rstd = rsqrtf(fmaxf(q, 0.f) * (1.f / 64.f) + 1e-5f);
        rstd_s[t] = rstd;

        unsigned short vv[32];
        #pragma unroll
        for (int j = 0; j < 11; ++j) vv[j] = f2bf(rstd * u[j]);
        vv[11] = f2bf(-rstd * mu);
        #pragma unroll
        for (int j = 12; j < 32; ++j) vv[j] = 0;
        #pragma unroll
        for (int c = 0; c < 4; ++c)
            *(s16x8*)((char*)VA + t * 64 + ((c ^ (t & 3)) * 16)) = *(const s16x8*)&vv[c * 8];
    } else if (t < 112) {
        rstd_s[t] = 0.f;
        s16x8 z = {0, 0, 0, 0, 0, 0, 0, 0};
        #pragma unroll
        for (int c = 0; c < 4; ++c)
            *(s16x8*)((char*)VA + t * 64 + c * 16) = z;
    }
    __syncthreads();   // barrier2: VA, rstd_s, cf_s ready

    // ---- MFMA V@M ----
    s16x8 bfr = *(const s16x8*)(PGmF + ((size_t)w * 64 + lane) * 8);
    f32x4 acc[7];
    #pragma unroll
    for (int mt = 0; mt < 7; ++mt) {
        int row = mt * 16 + (lane & 15);
        s16x8 a = *(const s16x8*)((char*)VA + row * 64 + ((kq ^ (row & 3)) * 16));
        f32x4 z = {0.f, 0.f, 0.f, 0.f};
        acc[mt] = __builtin_amdgcn_mfma_f32_16x16x32_bf16(a, bfr, z, 0, 0, 0);
    }

    // ---- chain + relu + pool ----
    float hbv = hb[colw], bgc = b_gcn[colw];
    float carry = 0.f, po = 0.f;
    #pragma unroll
    for (int mt = 0; mt < 7; ++mt) {
        int nb = mt * 16 + kq * 4;
        f32x4 rs4 = *(const f32x4*)&rstd_s[nb];
        f32x4 cf01 = *(const f32x4*)&cf_s[nb];
        f32x4 cf23 = *(const f32x4*)&cf_s[nb + 2];
        float hh[4];
        #pragma unroll
        for (int j = 0; j < 4; ++j)
            hh[j] = fmaf(rs4[j], pgv[mt][j], acc[mt][j]) + hbv;

        float hup = __shfl_up(hh[3], 16, 64);
        float hpj = (kq > 0) ? hup : carry;

        float o0 = fmaf(hh[0], cf01.x, fmaf(cf01.y, hpj, bgc));
        float o1 = fmaf(hh[1], cf01.z, fmaf(cf01.w, hh[0], bgc));
        float o2 = fmaf(hh[2], cf23.x, fmaf(cf23.y, hh[1], bgc));
        float o3 = fmaf(hh[3], cf23.z, fmaf(cf23.w, hh[2], bgc));
        if (nb < N_)     po += fmaxf(o0, 0.f);
        if (nb + 1 < N_) po += fmaxf(o1, 0.f);
        if (nb + 2 < N_) po += fmaxf(o2, 0.f);
        if (nb + 3 < N_) po += fmaxf(o3, 0.f);

        carry = __shfl(hh[3], 48 + (lane & 15), 64);
    }
    po += __shfl_xor(po, 16, 64);
    po += __shfl_xor(po, 32, 64);
    if (lane < 16) pooled[colw] = po * (1.f / (float)N_);
    __syncthreads();   // barrier3

    // ---- src output projection ----
    if (w == 0) {
        float o = b_out[lane];
        #pragma unroll
        for (int dk4 = 0; dk4 < 16; ++dk4) {
            f32x4 p4 = *(const f32x4*)&pooled[dk4 * 4];
            o = fmaf(p4.x, W_out[(dk4 * 4 + 0) * 64 + lane], o);
            o = fmaf(p4.y, W_out[(dk4 * 4 + 1) * 64 + lane], o);
            o = fmaf(p4.z, W_out[(dk4 * 4 + 2) * 64 + lane], o);
            o = fmaf(p4.w, W_out[(dk4 * 4 + 3) * 64 + lane], o);
        }
        out[(size_t)b * 64 + lane] = o;
    }
}

// ---------------------------------------------------------------------------
extern "C" void kernel_launch(void* const* d_in, const int* in_sizes, int n_in,
                              void* d_out, int out_size, void* d_ws, size_t ws_size,
                              hipStream_t stream)
{
    const int*   ids      = (const int*)d_in[0];
    const int*   eids     = (const int*)d_in[1];
    const float* times    = (const float*)d_in[2];
    const int*   dst_ids  = (const int*)d_in[3];
    const float* node_raw = (const float*)d_in[4];
    const float* edge_raw = (const float*)d_in[5];
    const float* W_feat   = (const float*)d_in[6];
    const float* b_feat   = (const float*)d_in[7];
    const float* W_edge   = (const float*)d_in[8];
    const float* b_edge   = (const float*)d_in[9];
    const float* W_time   = (const float*)d_in[10];
    const float* b_time   = (const float*)d_in[11];
    const float* W_struct = (const float*)d_in[12];
    const float* b_struct = (const float*)d_in[13];
    const float* w_tenc   = (const float*)d_in[14];
    const float* b_tenc   = (const float*)d_in[15];
    const float* ln_g     = (const float*)d_in[16];
    const float* ln_b     = (const float*)d_in[17];
    const float* W_gcn    = (const float*)d_in[18];
    const float* b_gcn    = (const float*)d_in[19];
    const float* W_out    = (const float*)d_in[20];
    const float* b_out    = (const float*)d_in[21];

    char* ws = (char*)d_ws;
    float*          proj   = (float*)ws;                          // 12,800,000 B
    int*            skill  = (int*)(ws + 12800000);               //    200,000 B
    float*          hb     = (float*)(ws + 13008192);             //        256 B
    float*          wmg    = (float*)(ws + 13008448);             //         64 B
    float*          Mg     = (float*)(ws + 13008512);             //        512 B
    unsigned short* PGmF   = (unsigned short*)(ws + 13009024);    //      4,096 B
    float*          stats  = (float*)(ws + 13100032);             //  3,200,000 B
    float*          projG  = (float*)(ws + 16400000);             // 12,800,000 B
    float*          dstE   = (float*)(ws + 29200000);             // 12,800,000 B

    k_pre<<<783, 256, 0, stream>>>(node_raw, W_feat, b_feat, W_gcn, ln_g, ln_b,
                                   W_edge, b_edge, W_time, b_time, W_struct, b_struct,
                                   proj, skill, hb, wmg, Mg, PGmF);
    k_pg<<<782, 256, 0, stream>>>(proj, W_gcn, ln_g, W_out, b_out,
                                  W_edge, b_edge, W_time, b_time, W_struct, b_struct,
                                  projG, dstE, stats);
    k_main<<<B_, 256, 0, stream>>>(ids, eids, times, dst_ids, edge_raw,
                                   w_tenc, b_tenc, b_gcn, W_out, b_out,
                                   projG, dstE, skill, hb, wmg, Mg, PGmF, stats,
                                   (float*)d_out);
}